// Round 5
// baseline (543.068 us; speedup 1.0000x reference)
//
#include <hip/hip_runtime.h>
#include <hip/hip_bf16.h>

#define N_NODES 100000
#define N_EDGES 1600000
#define BATCH   16384
#define HID     128

#define SHIFT 9
#define BSZ   512
#define NB    196
#define EPB   8192

typedef __attribute__((ext_vector_type(8))) short bf16x8;
typedef __attribute__((ext_vector_type(4))) float fx4;

__device__ inline short f2bf(float f) {
    unsigned u = __builtin_bit_cast(unsigned, f);
    unsigned r = (u + 0x7FFF + ((u >> 16) & 1)) >> 16;
    return (short)r;
}
__device__ inline float bf2f(short s) {
    unsigned u = ((unsigned)(unsigned short)s) << 16;
    return __builtin_bit_cast(float, u);
}

// ---------------- CSR build: bucketed two-pass ----------------

__global__ __launch_bounds__(256) void k_bhist(const int* __restrict__ dst,
                                               int* __restrict__ bcnt, int E) {
    __shared__ int lh[NB];
    int t = threadIdx.x;
    for (int j = t; j < NB; j += 256) lh[j] = 0;
    __syncthreads();
    int base = blockIdx.x * 4096;
    int n = min(4096, E - base);
    for (int i = t; i < n; i += 256) atomicAdd(&lh[dst[base + i] >> SHIFT], 1);
    __syncthreads();
    for (int j = t; j < NB; j += 256)
        if (lh[j]) atomicAdd(&bcnt[j], lh[j]);
}

__global__ void k_bscan(const int* __restrict__ bcnt, int* __restrict__ bbase,
                        int* __restrict__ bcur, int* __restrict__ offsets) {
    __shared__ int sh[256];
    int t = threadIdx.x;
    int c = (t < NB) ? bcnt[t] : 0;
    sh[t] = c;
    __syncthreads();
    for (int off = 1; off < 256; off <<= 1) {
        int v = 0;
        if (t >= off) v = sh[t - off];
        __syncthreads();
        if (t >= off) sh[t] += v;
        __syncthreads();
    }
    int incl = sh[t];
    int excl = incl - c;
    if (t < NB) { bbase[t] = excl; bcur[t] = excl; }
    if (t == NB - 1) { bbase[NB] = incl; offsets[N_NODES] = incl; }
}

__global__ __launch_bounds__(256) void k_passA(
    const int* __restrict__ edge, int* __restrict__ bcur,
    unsigned* __restrict__ tmp, int E) {
    __shared__ unsigned staged[EPB];
    __shared__ unsigned char bkt[EPB];
    __shared__ int lh[NB], lstart[NB], gbase[NB], lcur[NB];
    int t = threadIdx.x;
    int base = blockIdx.x * EPB;
    int n = min(EPB, E - base);
    for (int j = t; j < NB; j += 256) lh[j] = 0;
    __syncthreads();
    for (int i = t; i < n; i += 256)
        atomicAdd(&lh[edge[E + base + i] >> SHIFT], 1);
    __syncthreads();
    if (t == 0) {
        int run = 0;
        for (int b = 0; b < NB; ++b) { lstart[b] = run; run += lh[b]; }
    }
    __syncthreads();
    if (t < NB) {
        gbase[t] = atomicAdd(&bcur[t], lh[t]);
        lcur[t] = lstart[t];
    }
    __syncthreads();
    for (int i = t; i < n; i += 256) {
        int s = edge[base + i];
        int d = edge[E + base + i];
        int b = d >> SHIFT;
        unsigned p = (unsigned)s | ((unsigned)(d & (BSZ - 1)) << 17);
        int pos = atomicAdd(&lcur[b], 1);
        staged[pos] = p;
        bkt[pos] = (unsigned char)b;
    }
    __syncthreads();
    for (int i = t; i < n; i += 256) {
        int b = bkt[i];
        tmp[gbase[b] + (i - lstart[b])] = staged[i];
    }
}

__global__ __launch_bounds__(256) void k_passB(
    const unsigned* __restrict__ tmp, const int* __restrict__ bbase,
    int* __restrict__ offsets, float* __restrict__ dinv,
    int* __restrict__ col) {
    __shared__ int lh[BSZ];
    __shared__ int lsum[256];
    int b = blockIdx.x, t = threadIdx.x;
    int begin = bbase[b], end = bbase[b + 1];
    lh[t] = 0; lh[t + 256] = 0;
    __syncthreads();
    for (int i = begin + t; i < end; i += 256)
        atomicAdd(&lh[tmp[i] >> 17], 1);
    __syncthreads();
    int c0 = lh[2 * t], c1 = lh[2 * t + 1];
    int tsum = c0 + c1;
    lsum[t] = tsum;
    __syncthreads();
    for (int off = 1; off < 256; off <<= 1) {
        int v = 0;
        if (t >= off) v = lsum[t - off];
        __syncthreads();
        if (t >= off) lsum[t] += v;
        __syncthreads();
    }
    int texcl = lsum[t] - tsum;
    int node0 = (b << SHIFT) + 2 * t;
    if (node0 < N_NODES) {
        offsets[node0] = begin + texcl;
        dinv[node0] = rsqrtf((float)c0 + 1.f);
    }
    if (node0 + 1 < N_NODES) {
        offsets[node0 + 1] = begin + texcl + c0;
        dinv[node0 + 1] = rsqrtf((float)c1 + 1.f);
    }
    __syncthreads();
    lh[2 * t] = texcl;
    lh[2 * t + 1] = texcl + c0;
    __syncthreads();
    for (int i = begin + t; i < end; i += 1024) {
        int i1 = i + 256, i2 = i + 512, i3 = i + 768;
        unsigned p0 = tmp[i];
        unsigned p1 = (i1 < end) ? tmp[i1] : 0u;
        unsigned p2 = (i2 < end) ? tmp[i2] : 0u;
        unsigned p3 = (i3 < end) ? tmp[i3] : 0u;
        int pos0 = begin + atomicAdd(&lh[p0 >> 17], 1);
        col[pos0] = (int)(p0 & 0x1FFFFu);
        if (i1 < end) { int q = begin + atomicAdd(&lh[p1 >> 17], 1); col[q] = (int)(p1 & 0x1FFFFu); }
        if (i2 < end) { int q = begin + atomicAdd(&lh[p2 >> 17], 1); col[q] = (int)(p2 & 0x1FFFFu); }
        if (i3 < end) { int q = begin + atomicAdd(&lh[p3 >> 17], 1); col[q] = (int)(p3 & 0x1FFFFu); }
    }
}

// ---------------- weight prep: fp32 W[k][n] -> bf16 hi/lo, transposed [n][k] ----------------

__global__ void k_prepW(const float* __restrict__ Wc0, const float* __restrict__ Wc1,
                        const float* __restrict__ Wc2, const float* __restrict__ Wp,
                        const float* __restrict__ Ww,
                        short* __restrict__ outH, short* __restrict__ outL) {
    int c = blockIdx.x;
    const float* src;
    int koff = 0;
    if (c == 0) src = Wc0;
    else if (c == 1) src = Wc1;
    else if (c == 2) src = Wc2;
    else if (c < 6) { src = Wp; koff = (c - 3) * 128; }
    else { src = Ww; koff = (c - 6) * 128; }
    short* dh = outH + c * 16384;
    short* dl = outL + c * 16384;
    for (int i = threadIdx.x; i < 16384; i += 256) {
        int k = i >> 7, n = i & 127;
        float v = src[(size_t)(koff + k) * 128 + n];
        short h = f2bf(v);
        short l = f2bf(v - bf2f(h));
        dh[n * 128 + k] = h;
        dl[n * 128 + k] = l;
    }
}

// ---------------- x prep: fp32 -> bf16 hi/lo ----------------

__global__ __launch_bounds__(256) void k_prepX(const float* __restrict__ x,
                                               short* __restrict__ xh,
                                               short* __restrict__ xl, int n4) {
    int i = blockIdx.x * 256 + threadIdx.x;
    if (i >= n4) return;
    float4 v = ((const float4*)x)[i];
    short4 h, l;
    h.x = f2bf(v.x); l.x = f2bf(v.x - bf2f(h.x));
    h.y = f2bf(v.y); l.y = f2bf(v.y - bf2f(h.y));
    h.z = f2bf(v.z); l.z = f2bf(v.z - bf2f(h.z));
    h.w = f2bf(v.w); l.w = f2bf(v.w - bf2f(h.w));
    ((short4*)xh)[i] = h;
    ((short4*)xl)[i] = l;
}

// ---------------- zero-LDS register-direct split-bf16 MFMA GEMM ----------------
// out[M,128] = (Ah+Al)[gidx][:,128] @ W  via  Ah@Wh + Ah@Wl + Al@Wh
// block = 4 waves (2x2), wave tile 32 rows x 64 cols; grid = ceil(M/64).

__global__ __launch_bounds__(256) void k_rgemm(
    const short* __restrict__ Ah, const short* __restrict__ Al,
    const short* __restrict__ WTh, const short* __restrict__ WTl,
    float* __restrict__ out, short* __restrict__ outb,
    const int* __restrict__ gidx, const float* __restrict__ bias,
    const float* __restrict__ scale, int M, int accumulate) {
    int t = threadIdx.x;
    int lane = t & 63, wave = t >> 6;
    int wm = wave >> 1, wn = wave & 1;
    int l15 = lane & 15;
    int kq = (lane >> 4) << 3;           // element offset of 8-elem k-slice
    int rowBase = blockIdx.x << 6;
    int colBase = wn << 6;

    int r0i = rowBase + (wm << 5) + l15;
    int r1i = r0i + 16;
    long long ar0 = (r0i < M) ? (gidx ? (long long)gidx[r0i] : (long long)r0i) : -1;
    long long ar1 = (r1i < M) ? (gidx ? (long long)gidx[r1i] : (long long)r1i) : -1;

    fx4 acc[2][4];
#pragma unroll
    for (int i = 0; i < 2; ++i)
#pragma unroll
        for (int j = 0; j < 4; ++j) {
            acc[i][j][0] = 0.f; acc[i][j][1] = 0.f;
            acc[i][j][2] = 0.f; acc[i][j][3] = 0.f;
        }

#pragma unroll
    for (int ks = 0; ks < 4; ++ks) {
        int ko = (ks << 5) + kq;
        bf16x8 a0h = {0,0,0,0,0,0,0,0}, a0l = {0,0,0,0,0,0,0,0};
        bf16x8 a1h = {0,0,0,0,0,0,0,0}, a1l = {0,0,0,0,0,0,0,0};
        if (ar0 >= 0) {
            a0h = *(const bf16x8*)&Ah[ar0 * 128 + ko];
            a0l = *(const bf16x8*)&Al[ar0 * 128 + ko];
        }
        if (ar1 >= 0) {
            a1h = *(const bf16x8*)&Ah[ar1 * 128 + ko];
            a1l = *(const bf16x8*)&Al[ar1 * 128 + ko];
        }
#pragma unroll
        for (int fc = 0; fc < 4; ++fc) {
            int c = colBase + (fc << 4) + l15;
            size_t bo = ((size_t)c << 7) + ko;
            bf16x8 bh = *(const bf16x8*)&WTh[bo];
            bf16x8 bl = *(const bf16x8*)&WTl[bo];
            acc[0][fc] = __builtin_amdgcn_mfma_f32_16x16x32_bf16(a0h, bh, acc[0][fc], 0, 0, 0);
            acc[0][fc] = __builtin_amdgcn_mfma_f32_16x16x32_bf16(a0h, bl, acc[0][fc], 0, 0, 0);
            acc[0][fc] = __builtin_amdgcn_mfma_f32_16x16x32_bf16(a0l, bh, acc[0][fc], 0, 0, 0);
            acc[1][fc] = __builtin_amdgcn_mfma_f32_16x16x32_bf16(a1h, bh, acc[1][fc], 0, 0, 0);
            acc[1][fc] = __builtin_amdgcn_mfma_f32_16x16x32_bf16(a1h, bl, acc[1][fc], 0, 0, 0);
            acc[1][fc] = __builtin_amdgcn_mfma_f32_16x16x32_bf16(a1l, bh, acc[1][fc], 0, 0, 0);
        }
    }

    // C/D layout: col = lane&15 (within 16), row = (lane>>4)*4 + reg
    int rq = (lane >> 4) << 2;
#pragma unroll
    for (int fr = 0; fr < 2; ++fr) {
        int rb = rowBase + (wm << 5) + (fr << 4) + rq;
#pragma unroll
        for (int rg = 0; rg < 4; ++rg) {
            int r = rb + rg;
            if (r >= M) continue;
            float sc = scale ? scale[r] : 1.f;
#pragma unroll
            for (int fc = 0; fc < 4; ++fc) {
                int cg = colBase + (fc << 4) + l15;
                float v = acc[fr][fc][rg] * sc;
                if (bias) v += bias[cg];
                size_t oo = ((size_t)r << 7) + cg;
                if (outb) {
                    outb[oo] = f2bf(v);
                } else {
                    if (accumulate) v += out[oo];
                    out[oo] = v;
                }
            }
        }
    }
}

// ---------------- Aggregation over bf16 h', writes split hi/lo bf16 ----------------
// o[v] = relu(dinv[v]*(sum h'[col[e]] + h'[v]) + bias); out as (oh, ol) bf16 pair.

__global__ __launch_bounds__(256) void k_agg(
    const short* __restrict__ h, const int* __restrict__ col,
    const int* __restrict__ offs, const float* __restrict__ dinv,
    const float* __restrict__ bias, short* __restrict__ xoh,
    short* __restrict__ xol, int n) {
    int lane = threadIdx.x & 63;
    int g = lane >> 4;
    int li = lane & 15;
    int v = (blockIdx.x << 2) + (threadIdx.x >> 6);
    if (v >= n) return;
    int beg = offs[v], end = offs[v + 1];
    float dv = dinv[v];
    float a[8];
#pragma unroll
    for (int j = 0; j < 8; ++j) a[j] = 0.f;
    if (g == 0) {
        bf16x8 hv = *(const bf16x8*)&h[(size_t)v * 128 + (li << 3)];
#pragma unroll
        for (int j = 0; j < 8; ++j) a[j] = bf2f(hv[j]);
    }
    int e = beg + g;
    for (; e + 4 < end; e += 8) {
        int sA = col[e], sB = col[e + 4];
        bf16x8 xA = *(const bf16x8*)&h[(size_t)sA * 128 + (li << 3)];
        bf16x8 xB = *(const bf16x8*)&h[(size_t)sB * 128 + (li << 3)];
#pragma unroll
        for (int j = 0; j < 8; ++j) a[j] += bf2f(xA[j]) + bf2f(xB[j]);
    }
    if (e < end) {
        bf16x8 xA = *(const bf16x8*)&h[(size_t)col[e] * 128 + (li << 3)];
#pragma unroll
        for (int j = 0; j < 8; ++j) a[j] += bf2f(xA[j]);
    }
#pragma unroll
    for (int off = 16; off <= 32; off <<= 1)
#pragma unroll
        for (int j = 0; j < 8; ++j) a[j] += __shfl_xor(a[j], off);
    if (g == 0) {
        float4 b0 = *(const float4*)&bias[li << 3];
        float4 b1 = *(const float4*)&bias[(li << 3) + 4];
        float o[8];
        o[0] = fmaxf(fmaf(a[0], dv, b0.x), 0.f);
        o[1] = fmaxf(fmaf(a[1], dv, b0.y), 0.f);
        o[2] = fmaxf(fmaf(a[2], dv, b0.z), 0.f);
        o[3] = fmaxf(fmaf(a[3], dv, b0.w), 0.f);
        o[4] = fmaxf(fmaf(a[4], dv, b1.x), 0.f);
        o[5] = fmaxf(fmaf(a[5], dv, b1.y), 0.f);
        o[6] = fmaxf(fmaf(a[6], dv, b1.z), 0.f);
        o[7] = fmaxf(fmaf(a[7], dv, b1.w), 0.f);
        bf16x8 hh, ll;
#pragma unroll
        for (int j = 0; j < 8; ++j) {
            short hb = f2bf(o[j]);
            hh[j] = hb;
            ll[j] = f2bf(o[j] - bf2f(hb));
        }
        *(bf16x8*)&xoh[(size_t)v * 128 + (li << 3)] = hh;
        *(bf16x8*)&xol[(size_t)v * 128 + (li << 3)] = ll;
    }
}

// ---------------- Final dot ----------------

__global__ __launch_bounds__(256) void k_dot(
    const float* __restrict__ P, const float* __restrict__ Q,
    float* __restrict__ out, int B) {
    int lane = threadIdx.x & 63;
    int b = (blockIdx.x << 2) + (threadIdx.x >> 6);
    if (b >= B) return;
    float2 p = *(const float2*)&P[(size_t)b * 128 + lane * 2];
    float2 q = *(const float2*)&Q[(size_t)b * 128 + lane * 2];
    float s = p.x * q.x + p.y * q.y;
#pragma unroll
    for (int off = 32; off; off >>= 1) s += __shfl_down(s, off);
    if (lane == 0) out[b] = s;
}

// ---------------- launch ----------------

extern "C" void kernel_launch(void* const* d_in, const int* in_sizes, int n_in,
                              void* d_out, int out_size, void* d_ws, size_t ws_size,
                              hipStream_t stream) {
    const float* x    = (const float*)d_in[0];
    const int*   edge = (const int*)d_in[1];
    const int*   sidx = (const int*)d_in[2];
    const int*   tidx = (const int*)d_in[3];
    const float* Wc0  = (const float*)d_in[4];
    const float* bc0  = (const float*)d_in[5];
    const float* Wc1  = (const float*)d_in[6];
    const float* bc1  = (const float*)d_in[7];
    const float* Wc2  = (const float*)d_in[8];
    const float* bc2  = (const float*)d_in[9];
    const float* Ww   = (const float*)d_in[10];
    const float* bw   = (const float*)d_in[11];
    const float* Wp   = (const float*)d_in[12];
    const float* bp   = (const float*)d_in[13];
    float* out = (float*)d_out;

    char* base = (char*)d_ws;
    size_t off = 0;
    auto alloc = [&](size_t bytes) -> char* {
        char* p = base + off;
        off = (off + bytes + 255) & ~(size_t)255;
        return p;
    };
    const size_t HSZ = (size_t)N_NODES * HID * sizeof(short);   // 25.6 MB
    short* xh   = (short*)alloc(HSZ);    // aliased: layer-2 agg out hi
    short* xl   = (short*)alloc(HSZ);    // aliased: layer-2 agg out lo
    short* a1h  = (short*)alloc(HSZ);
    short* a1l  = (short*)alloc(HSZ);
    short* hbf  = (short*)alloc(HSZ);
    float* Pm   = (float*)alloc((size_t)BATCH * HID * sizeof(float));
    float* Qm   = (float*)alloc((size_t)BATCH * HID * sizeof(float));
    int*   offsets = (int*)alloc((size_t)(N_NODES + 1) * sizeof(int));
    int*   colArr  = (int*)alloc((size_t)N_EDGES * sizeof(int));
    unsigned* tmp  = (unsigned*)alloc((size_t)N_EDGES * sizeof(unsigned));
    float* dinv    = (float*)alloc((size_t)N_NODES * sizeof(float));
    int*   bcnt    = (int*)alloc(256 * sizeof(int));
    int*   bbase   = (int*)alloc(256 * sizeof(int));
    int*   bcur    = (int*)alloc(256 * sizeof(int));
    short* wtH     = (short*)alloc((size_t)9 * 16384 * sizeof(short));
    short* wtL     = (short*)alloc((size_t)9 * 16384 * sizeof(short));
    short* a2h = xh, *a2l = xl;          // reuse x split region after layer-1 GEMM
    (void)ws_size; (void)in_sizes; (void)n_in; (void)out_size;

    // ---- CSR build (bucketed) ----
    hipMemsetAsync(bcnt, 0, NB * sizeof(int), stream);
    k_bhist<<<(N_EDGES + 4095) / 4096, 256, 0, stream>>>(edge + N_EDGES, bcnt, N_EDGES);
    k_bscan<<<1, 256, 0, stream>>>(bcnt, bbase, bcur, offsets);
    k_passA<<<(N_EDGES + EPB - 1) / EPB, 256, 0, stream>>>(edge, bcur, tmp, N_EDGES);
    k_passB<<<NB, 256, 0, stream>>>(tmp, bbase, offsets, dinv, colArr);

    // ---- prep ----
    k_prepW<<<9, 256, 0, stream>>>(Wc0, Wc1, Wc2, Wp, Ww, wtH, wtL);
    k_prepX<<<(N_NODES * HID / 4 + 255) / 256, 256, 0, stream>>>(x, xh, xl, N_NODES * HID / 4);

    const int gridN = (N_NODES + 63) / 64;   // 1563
    const int gridB = BATCH / 64;            // 256
    const int aggGrid = (N_NODES + 3) / 4;
    const int dotGrid = (BATCH + 3) / 4;
#define WT(c) (wtH + (c) * 16384), (wtL + (c) * 16384)

    // ---- layer 1 ----
    k_rgemm<<<gridN, 256, 0, stream>>>(xh, xl, WT(0), nullptr, hbf, nullptr, nullptr, dinv, N_NODES, 0);
    k_agg<<<aggGrid, 256, 0, stream>>>(hbf, colArr, offsets, dinv, bc0, a1h, a1l, N_NODES);
    k_rgemm<<<gridB, 256, 0, stream>>>(a1h, a1l, WT(3), Pm, nullptr, sidx, bp, nullptr, BATCH, 0);
    k_rgemm<<<gridB, 256, 0, stream>>>(a1h, a1l, WT(6), Qm, nullptr, tidx, bw, nullptr, BATCH, 0);

    // ---- layer 2 ----
    k_rgemm<<<gridN, 256, 0, stream>>>(a1h, a1l, WT(1), nullptr, hbf, nullptr, nullptr, dinv, N_NODES, 0);
    k_agg<<<aggGrid, 256, 0, stream>>>(hbf, colArr, offsets, dinv, bc1, a2h, a2l, N_NODES);
    k_rgemm<<<gridB, 256, 0, stream>>>(a2h, a2l, WT(4), Pm, nullptr, sidx, nullptr, nullptr, BATCH, 1);
    k_rgemm<<<gridB, 256, 0, stream>>>(a2h, a2l, WT(7), Qm, nullptr, tidx, nullptr, nullptr, BATCH, 1);

    // ---- layer 3 ----
    k_rgemm<<<gridN, 256, 0, stream>>>(a2h, a2l, WT(2), nullptr, hbf, nullptr, nullptr, dinv, N_NODES, 0);
    k_agg<<<aggGrid, 256, 0, stream>>>(hbf, colArr, offsets, dinv, bc2, a1h, a1l, N_NODES);
    k_rgemm<<<gridB, 256, 0, stream>>>(a1h, a1l, WT(5), Pm, nullptr, sidx, nullptr, nullptr, BATCH, 1);
    k_rgemm<<<gridB, 256, 0, stream>>>(a1h, a1l, WT(8), Qm, nullptr, tidx, nullptr, nullptr, BATCH, 1);

    // ---- score ----
    k_dot<<<dotGrid, 256, 0, stream>>>(Pm, Qm, out, BATCH);
}

// Round 6
// 428.720 us; speedup vs baseline: 1.2667x; 1.2667x over previous
//
#include <hip/hip_runtime.h>
#include <hip/hip_bf16.h>

#define N_NODES 100000
#define N_EDGES 1600000
#define BATCH   16384
#define HID     128

#define SHIFT 9
#define BSZ   512
#define NB    196
#define EPB   8192

typedef __attribute__((ext_vector_type(8))) short bf16x8;
typedef __attribute__((ext_vector_type(4))) float fx4;
typedef __attribute__((ext_vector_type(2))) float fx2;

__device__ inline short f2bf(float f) {
    unsigned u = __builtin_bit_cast(unsigned, f);
    unsigned r = (u + 0x7FFF + ((u >> 16) & 1)) >> 16;
    return (short)r;
}
__device__ inline float bf2f(short s) {
    unsigned u = ((unsigned)(unsigned short)s) << 16;
    return __builtin_bit_cast(float, u);
}

// ---------------- CSR build: bucketed two-pass (unchanged) ----------------

__global__ __launch_bounds__(256) void k_bhist(const int* __restrict__ dst,
                                               int* __restrict__ bcnt, int E) {
    __shared__ int lh[NB];
    int t = threadIdx.x;
    for (int j = t; j < NB; j += 256) lh[j] = 0;
    __syncthreads();
    int base = blockIdx.x * 4096;
    int n = min(4096, E - base);
    for (int i = t; i < n; i += 256) atomicAdd(&lh[dst[base + i] >> SHIFT], 1);
    __syncthreads();
    for (int j = t; j < NB; j += 256)
        if (lh[j]) atomicAdd(&bcnt[j], lh[j]);
}

__global__ void k_bscan(const int* __restrict__ bcnt, int* __restrict__ bbase,
                        int* __restrict__ bcur, int* __restrict__ offsets) {
    __shared__ int sh[256];
    int t = threadIdx.x;
    int c = (t < NB) ? bcnt[t] : 0;
    sh[t] = c;
    __syncthreads();
    for (int off = 1; off < 256; off <<= 1) {
        int v = 0;
        if (t >= off) v = sh[t - off];
        __syncthreads();
        if (t >= off) sh[t] += v;
        __syncthreads();
    }
    int incl = sh[t];
    int excl = incl - c;
    if (t < NB) { bbase[t] = excl; bcur[t] = excl; }
    if (t == NB - 1) { bbase[NB] = incl; offsets[N_NODES] = incl; }
}

__global__ __launch_bounds__(256) void k_passA(
    const int* __restrict__ edge, int* __restrict__ bcur,
    unsigned* __restrict__ tmp, int E) {
    __shared__ unsigned staged[EPB];
    __shared__ unsigned char bkt[EPB];
    __shared__ int lh[NB], lstart[NB], gbase[NB], lcur[NB];
    int t = threadIdx.x;
    int base = blockIdx.x * EPB;
    int n = min(EPB, E - base);
    for (int j = t; j < NB; j += 256) lh[j] = 0;
    __syncthreads();
    for (int i = t; i < n; i += 256)
        atomicAdd(&lh[edge[E + base + i] >> SHIFT], 1);
    __syncthreads();
    if (t == 0) {
        int run = 0;
        for (int b = 0; b < NB; ++b) { lstart[b] = run; run += lh[b]; }
    }
    __syncthreads();
    if (t < NB) {
        gbase[t] = atomicAdd(&bcur[t], lh[t]);
        lcur[t] = lstart[t];
    }
    __syncthreads();
    for (int i = t; i < n; i += 256) {
        int s = edge[base + i];
        int d = edge[E + base + i];
        int b = d >> SHIFT;
        unsigned p = (unsigned)s | ((unsigned)(d & (BSZ - 1)) << 17);
        int pos = atomicAdd(&lcur[b], 1);
        staged[pos] = p;
        bkt[pos] = (unsigned char)b;
    }
    __syncthreads();
    for (int i = t; i < n; i += 256) {
        int b = bkt[i];
        tmp[gbase[b] + (i - lstart[b])] = staged[i];
    }
}

__global__ __launch_bounds__(256) void k_passB(
    const unsigned* __restrict__ tmp, const int* __restrict__ bbase,
    int* __restrict__ offsets, float* __restrict__ dinv,
    int* __restrict__ col) {
    __shared__ int lh[BSZ];
    __shared__ int lsum[256];
    int b = blockIdx.x, t = threadIdx.x;
    int begin = bbase[b], end = bbase[b + 1];
    lh[t] = 0; lh[t + 256] = 0;
    __syncthreads();
    for (int i = begin + t; i < end; i += 256)
        atomicAdd(&lh[tmp[i] >> 17], 1);
    __syncthreads();
    int c0 = lh[2 * t], c1 = lh[2 * t + 1];
    int tsum = c0 + c1;
    lsum[t] = tsum;
    __syncthreads();
    for (int off = 1; off < 256; off <<= 1) {
        int v = 0;
        if (t >= off) v = lsum[t - off];
        __syncthreads();
        if (t >= off) lsum[t] += v;
        __syncthreads();
    }
    int texcl = lsum[t] - tsum;
    int node0 = (b << SHIFT) + 2 * t;
    if (node0 < N_NODES) {
        offsets[node0] = begin + texcl;
        dinv[node0] = rsqrtf((float)c0 + 1.f);
    }
    if (node0 + 1 < N_NODES) {
        offsets[node0 + 1] = begin + texcl + c0;
        dinv[node0 + 1] = rsqrtf((float)c1 + 1.f);
    }
    __syncthreads();
    lh[2 * t] = texcl;
    lh[2 * t + 1] = texcl + c0;
    __syncthreads();
    for (int i = begin + t; i < end; i += 1024) {
        int i1 = i + 256, i2 = i + 512, i3 = i + 768;
        unsigned p0 = tmp[i];
        unsigned p1 = (i1 < end) ? tmp[i1] : 0u;
        unsigned p2 = (i2 < end) ? tmp[i2] : 0u;
        unsigned p3 = (i3 < end) ? tmp[i3] : 0u;
        int pos0 = begin + atomicAdd(&lh[p0 >> 17], 1);
        col[pos0] = (int)(p0 & 0x1FFFFu);
        if (i1 < end) { int q = begin + atomicAdd(&lh[p1 >> 17], 1); col[q] = (int)(p1 & 0x1FFFFu); }
        if (i2 < end) { int q = begin + atomicAdd(&lh[p2 >> 17], 1); col[q] = (int)(p2 & 0x1FFFFu); }
        if (i3 < end) { int q = begin + atomicAdd(&lh[p3 >> 17], 1); col[q] = (int)(p3 & 0x1FFFFu); }
    }
}

// ---------------- weight prep: fp32 W[k][n] -> bf16 hi/lo, transposed [n][k] ----------------

__global__ void k_prepW(const float* __restrict__ Wc0, const float* __restrict__ Wc1,
                        const float* __restrict__ Wc2, const float* __restrict__ Wp,
                        const float* __restrict__ Ww,
                        short* __restrict__ outH, short* __restrict__ outL) {
    int c = blockIdx.x;
    const float* src;
    int koff = 0;
    if (c == 0) src = Wc0;
    else if (c == 1) src = Wc1;
    else if (c == 2) src = Wc2;
    else if (c < 6) { src = Wp; koff = (c - 3) * 128; }
    else { src = Ww; koff = (c - 6) * 128; }
    short* dh = outH + c * 16384;
    short* dl = outL + c * 16384;
    for (int i = threadIdx.x; i < 16384; i += 256) {
        int k = i >> 7, n = i & 127;
        float v = src[(size_t)(koff + k) * 128 + n];
        short h = f2bf(v);
        short l = f2bf(v - bf2f(h));
        dh[n * 128 + k] = h;
        dl[n * 128 + k] = l;
    }
}

// ---------------- split helper: 8 fp32 -> bf16 hi/lo ----------------

__device__ inline void split8(const float* p, bf16x8& h8, bf16x8& l8) {
    float4 va = *(const float4*)p;
    float4 vb = *(const float4*)(p + 4);
    float vv[8] = {va.x, va.y, va.z, va.w, vb.x, vb.y, vb.z, vb.w};
#pragma unroll
    for (int j = 0; j < 8; ++j) {
        short hb = f2bf(vv[j]);
        h8[j] = hb;
        l8[j] = f2bf(vv[j] - bf2f(hb));
    }
}

// ---------------- layer-1 GEMM: fp32 A, in-register split, bf16 out ----------------
// outb[r] = (A[r] @ W) * scale[r]; block 64 rows, 4 waves 2x2, wave 32x64.

__global__ __launch_bounds__(256) void k_rgemm32(
    const float* __restrict__ A, const short* __restrict__ WTh,
    const short* __restrict__ WTl, short* __restrict__ outb,
    const float* __restrict__ scale, int M) {
    int t = threadIdx.x;
    int lane = t & 63, wave = t >> 6;
    int wm = wave >> 1, wn = wave & 1;
    int l15 = lane & 15;
    int kq = (lane >> 4) << 3;
    int rowBase = blockIdx.x << 6;
    int colBase = wn << 6;
    int r0i = rowBase + (wm << 5) + l15;
    int r1i = r0i + 16;

    fx4 acc[2][4];
#pragma unroll
    for (int i = 0; i < 2; ++i)
#pragma unroll
        for (int j = 0; j < 4; ++j) {
            acc[i][j][0] = 0.f; acc[i][j][1] = 0.f;
            acc[i][j][2] = 0.f; acc[i][j][3] = 0.f;
        }

#pragma unroll
    for (int ks = 0; ks < 4; ++ks) {
        int ko = (ks << 5) + kq;
        bf16x8 a0h = {0,0,0,0,0,0,0,0}, a0l = {0,0,0,0,0,0,0,0};
        bf16x8 a1h = {0,0,0,0,0,0,0,0}, a1l = {0,0,0,0,0,0,0,0};
        if (r0i < M) split8(&A[(size_t)r0i * 128 + ko], a0h, a0l);
        if (r1i < M) split8(&A[(size_t)r1i * 128 + ko], a1h, a1l);
#pragma unroll
        for (int fc = 0; fc < 4; ++fc) {
            int c = colBase + (fc << 4) + l15;
            size_t bo = ((size_t)c << 7) + ko;
            bf16x8 bh = *(const bf16x8*)&WTh[bo];
            bf16x8 bl = *(const bf16x8*)&WTl[bo];
            acc[0][fc] = __builtin_amdgcn_mfma_f32_16x16x32_bf16(a0h, bh, acc[0][fc], 0, 0, 0);
            acc[0][fc] = __builtin_amdgcn_mfma_f32_16x16x32_bf16(a0h, bl, acc[0][fc], 0, 0, 0);
            acc[0][fc] = __builtin_amdgcn_mfma_f32_16x16x32_bf16(a0l, bh, acc[0][fc], 0, 0, 0);
            acc[1][fc] = __builtin_amdgcn_mfma_f32_16x16x32_bf16(a1h, bh, acc[1][fc], 0, 0, 0);
            acc[1][fc] = __builtin_amdgcn_mfma_f32_16x16x32_bf16(a1h, bl, acc[1][fc], 0, 0, 0);
            acc[1][fc] = __builtin_amdgcn_mfma_f32_16x16x32_bf16(a1l, bh, acc[1][fc], 0, 0, 0);
        }
    }

    int rq = (lane >> 4) << 2;
#pragma unroll
    for (int fr = 0; fr < 2; ++fr) {
        int rb = rowBase + (wm << 5) + (fr << 4) + rq;
#pragma unroll
        for (int rg = 0; rg < 4; ++rg) {
            int r = rb + rg;
            if (r >= M) continue;
            float sc = scale[r];
#pragma unroll
            for (int fc = 0; fc < 4; ++fc) {
                int cg = colBase + (fc << 4) + l15;
                outb[((size_t)r << 7) + cg] = f2bf(acc[fr][fc][rg] * sc);
            }
        }
    }
}

// ---------------- conv GEMM: split-bf16 A, bf16 out ----------------

__global__ __launch_bounds__(256) void k_rgemm(
    const short* __restrict__ Ah, const short* __restrict__ Al,
    const short* __restrict__ WTh, const short* __restrict__ WTl,
    short* __restrict__ outb, const float* __restrict__ scale, int M) {
    int t = threadIdx.x;
    int lane = t & 63, wave = t >> 6;
    int wm = wave >> 1, wn = wave & 1;
    int l15 = lane & 15;
    int kq = (lane >> 4) << 3;
    int rowBase = blockIdx.x << 6;
    int colBase = wn << 6;
    int r0i = rowBase + (wm << 5) + l15;
    int r1i = r0i + 16;
    long long ar0 = (r0i < M) ? (long long)r0i : -1;
    long long ar1 = (r1i < M) ? (long long)r1i : -1;

    fx4 acc[2][4];
#pragma unroll
    for (int i = 0; i < 2; ++i)
#pragma unroll
        for (int j = 0; j < 4; ++j) {
            acc[i][j][0] = 0.f; acc[i][j][1] = 0.f;
            acc[i][j][2] = 0.f; acc[i][j][3] = 0.f;
        }

#pragma unroll
    for (int ks = 0; ks < 4; ++ks) {
        int ko = (ks << 5) + kq;
        bf16x8 a0h = {0,0,0,0,0,0,0,0}, a0l = {0,0,0,0,0,0,0,0};
        bf16x8 a1h = {0,0,0,0,0,0,0,0}, a1l = {0,0,0,0,0,0,0,0};
        if (ar0 >= 0) {
            a0h = *(const bf16x8*)&Ah[ar0 * 128 + ko];
            a0l = *(const bf16x8*)&Al[ar0 * 128 + ko];
        }
        if (ar1 >= 0) {
            a1h = *(const bf16x8*)&Ah[ar1 * 128 + ko];
            a1l = *(const bf16x8*)&Al[ar1 * 128 + ko];
        }
#pragma unroll
        for (int fc = 0; fc < 4; ++fc) {
            int c = colBase + (fc << 4) + l15;
            size_t bo = ((size_t)c << 7) + ko;
            bf16x8 bh = *(const bf16x8*)&WTh[bo];
            bf16x8 bl = *(const bf16x8*)&WTl[bo];
            acc[0][fc] = __builtin_amdgcn_mfma_f32_16x16x32_bf16(a0h, bh, acc[0][fc], 0, 0, 0);
            acc[0][fc] = __builtin_amdgcn_mfma_f32_16x16x32_bf16(a0h, bl, acc[0][fc], 0, 0, 0);
            acc[0][fc] = __builtin_amdgcn_mfma_f32_16x16x32_bf16(a0l, bh, acc[0][fc], 0, 0, 0);
            acc[1][fc] = __builtin_amdgcn_mfma_f32_16x16x32_bf16(a1h, bh, acc[1][fc], 0, 0, 0);
            acc[1][fc] = __builtin_amdgcn_mfma_f32_16x16x32_bf16(a1h, bl, acc[1][fc], 0, 0, 0);
            acc[1][fc] = __builtin_amdgcn_mfma_f32_16x16x32_bf16(a1l, bh, acc[1][fc], 0, 0, 0);
        }
    }

    int rq = (lane >> 4) << 2;
#pragma unroll
    for (int fr = 0; fr < 2; ++fr) {
        int rb = rowBase + (wm << 5) + (fr << 4) + rq;
#pragma unroll
        for (int rg = 0; rg < 4; ++rg) {
            int r = rb + rg;
            if (r >= M) continue;
            float sc = scale[r];
#pragma unroll
            for (int fc = 0; fc < 4; ++fc) {
                int cg = colBase + (fc << 4) + l15;
                outb[((size_t)r << 7) + cg] = f2bf(acc[fr][fc][rg] * sc);
            }
        }
    }
}

// ---------------- aggregation core ----------------
// packed accumulate: each u32 holds 2 bf16; unpack with shl/and, add as float2.

__device__ inline void addrow(uint4 u, fx2* a) {
    a[0] += (fx2){__builtin_bit_cast(float, u.x << 16),
                  __builtin_bit_cast(float, u.x & 0xFFFF0000u)};
    a[1] += (fx2){__builtin_bit_cast(float, u.y << 16),
                  __builtin_bit_cast(float, u.y & 0xFFFF0000u)};
    a[2] += (fx2){__builtin_bit_cast(float, u.z << 16),
                  __builtin_bit_cast(float, u.z & 0xFFFF0000u)};
    a[3] += (fx2){__builtin_bit_cast(float, u.w << 16),
                  __builtin_bit_cast(float, u.w & 0xFFFF0000u)};
}

__device__ inline void agg_body(const short* __restrict__ h,
                                const int* __restrict__ col,
                                const int* __restrict__ offs,
                                const float* __restrict__ dinv,
                                const float* __restrict__ bias,
                                short* __restrict__ xoh,
                                short* __restrict__ xol,
                                int v, int orow) {
    int lane = threadIdx.x & 63;
    int g = lane >> 4;
    int li = lane & 15;
    int beg = offs[v], end = offs[v + 1];
    float dv = dinv[v];
    fx2 a4[4] = {{0.f,0.f},{0.f,0.f},{0.f,0.f},{0.f,0.f}};
    if (g == 0)
        addrow(*(const uint4*)&h[(size_t)v * 128 + (li << 3)], a4);
    int e = beg + g;
    for (; e + 12 < end; e += 16) {
        int s0 = col[e], s1 = col[e + 4], s2 = col[e + 8], s3 = col[e + 12];
        uint4 u0 = *(const uint4*)&h[(size_t)s0 * 128 + (li << 3)];
        uint4 u1 = *(const uint4*)&h[(size_t)s1 * 128 + (li << 3)];
        uint4 u2 = *(const uint4*)&h[(size_t)s2 * 128 + (li << 3)];
        uint4 u3 = *(const uint4*)&h[(size_t)s3 * 128 + (li << 3)];
        addrow(u0, a4); addrow(u1, a4); addrow(u2, a4); addrow(u3, a4);
    }
    for (; e < end; e += 4)
        addrow(*(const uint4*)&h[(size_t)col[e] * 128 + (li << 3)], a4);

    float a[8];
#pragma unroll
    for (int j = 0; j < 4; ++j) { a[2 * j] = a4[j][0]; a[2 * j + 1] = a4[j][1]; }
#pragma unroll
    for (int off = 16; off <= 32; off <<= 1)
#pragma unroll
        for (int j = 0; j < 8; ++j) a[j] += __shfl_xor(a[j], off);
    if (g == 0) {
        bf16x8 hh, ll;
#pragma unroll
        for (int j = 0; j < 8; ++j) {
            float o = fmaxf(fmaf(a[j], dv, bias[(li << 3) + j]), 0.f);
            short hb = f2bf(o);
            hh[j] = hb;
            ll[j] = f2bf(o - bf2f(hb));
        }
        *(bf16x8*)&xoh[(size_t)orow * 128 + (li << 3)] = hh;
        *(bf16x8*)&xol[(size_t)orow * 128 + (li << 3)] = ll;
    }
}

__global__ __launch_bounds__(256) void k_agg(
    const short* __restrict__ h, const int* __restrict__ col,
    const int* __restrict__ offs, const float* __restrict__ dinv,
    const float* __restrict__ bias, short* __restrict__ xoh,
    short* __restrict__ xol, int n) {
    int v = (blockIdx.x << 2) + (threadIdx.x >> 6);
    if (v >= n) return;
    agg_body(h, col, offs, dinv, bias, xoh, xol, v, v);
}

// layer-3: aggregate only the 32768 batch nodes (sidx || tidx), compact output.
__global__ __launch_bounds__(256) void k_agg3(
    const short* __restrict__ h, const int* __restrict__ col,
    const int* __restrict__ offs, const float* __restrict__ dinv,
    const float* __restrict__ bias, short* __restrict__ xoh,
    short* __restrict__ xol, const int* __restrict__ sidx,
    const int* __restrict__ tidx) {
    int i = (blockIdx.x << 2) + (threadIdx.x >> 6);
    if (i >= 2 * BATCH) return;
    int v = (i < BATCH) ? sidx[i] : tidx[i - BATCH];
    agg_body(h, col, offs, dinv, bias, xoh, xol, v, i);
}

// ---------------- fused P/Q projection: K=384 over 3 chunks ----------------
// blocks 0..255: P (sidx, Wp, bp); 256..511: Q (tidx, Ww, bw).

__global__ __launch_bounds__(256) void k_pq(
    const short* __restrict__ a1h, const short* __restrict__ a1l,
    const short* __restrict__ a2h, const short* __restrict__ a2l,
    const short* __restrict__ x3h, const short* __restrict__ x3l,
    const short* __restrict__ wtH, const short* __restrict__ wtL,
    const int* __restrict__ sidx, const int* __restrict__ tidx,
    const float* __restrict__ bp, const float* __restrict__ bw,
    float* __restrict__ Pm, float* __restrict__ Qm) {
    int blk = blockIdx.x;
    int isQ = blk >> 8;
    int mtile = blk & 255;
    const int* gidx = isQ ? tidx : sidx;
    const float* bias = isQ ? bw : bp;
    float* outp = isQ ? Qm : Pm;
    int x3off = isQ << 14;

    int t = threadIdx.x;
    int lane = t & 63, wave = t >> 6;
    int wm = wave >> 1, wn = wave & 1;
    int l15 = lane & 15;
    int kq = (lane >> 4) << 3;
    int rowBase = mtile << 6;
    int colBase = wn << 6;
    int r0i = rowBase + (wm << 5) + l15;
    int r1i = r0i + 16;
    long long n0 = (long long)gidx[r0i];
    long long n1 = (long long)gidx[r1i];

    fx4 acc[2][4];
#pragma unroll
    for (int i = 0; i < 2; ++i)
#pragma unroll
        for (int j = 0; j < 4; ++j) {
            acc[i][j][0] = 0.f; acc[i][j][1] = 0.f;
            acc[i][j][2] = 0.f; acc[i][j][3] = 0.f;
        }

#pragma unroll
    for (int c = 0; c < 3; ++c) {
        const short* Ah = (c == 0) ? a1h : (c == 1) ? a2h : x3h;
        const short* Al = (c == 0) ? a1l : (c == 1) ? a2l : x3l;
        long long b0 = (c == 2) ? (long long)(r0i + x3off) : n0;
        long long b1 = (c == 2) ? (long long)(r1i + x3off) : n1;
        const short* Bh = wtH + (size_t)(3 + isQ * 3 + c) * 16384;
        const short* Bl = wtL + (size_t)(3 + isQ * 3 + c) * 16384;
#pragma unroll
        for (int ks = 0; ks < 4; ++ks) {
            int ko = (ks << 5) + kq;
            bf16x8 a0h = *(const bf16x8*)&Ah[b0 * 128 + ko];
            bf16x8 a0l = *(const bf16x8*)&Al[b0 * 128 + ko];
            bf16x8 a1h_ = *(const bf16x8*)&Ah[b1 * 128 + ko];
            bf16x8 a1l_ = *(const bf16x8*)&Al[b1 * 128 + ko];
#pragma unroll
            for (int fc = 0; fc < 4; ++fc) {
                int cc = colBase + (fc << 4) + l15;
                size_t bo = ((size_t)cc << 7) + ko;
                bf16x8 bh = *(const bf16x8*)&Bh[bo];
                bf16x8 bl = *(const bf16x8*)&Bl[bo];
                acc[0][fc] = __builtin_amdgcn_mfma_f32_16x16x32_bf16(a0h, bh, acc[0][fc], 0, 0, 0);
                acc[0][fc] = __builtin_amdgcn_mfma_f32_16x16x32_bf16(a0h, bl, acc[0][fc], 0, 0, 0);
                acc[0][fc] = __builtin_amdgcn_mfma_f32_16x16x32_bf16(a0l, bh, acc[0][fc], 0, 0, 0);
                acc[1][fc] = __builtin_amdgcn_mfma_f32_16x16x32_bf16(a1h_, bh, acc[1][fc], 0, 0, 0);
                acc[1][fc] = __builtin_amdgcn_mfma_f32_16x16x32_bf16(a1h_, bl, acc[1][fc], 0, 0, 0);
                acc[1][fc] = __builtin_amdgcn_mfma_f32_16x16x32_bf16(a1l_, bh, acc[1][fc], 0, 0, 0);
            }
        }
    }

    int rq = (lane >> 4) << 2;
#pragma unroll
    for (int fr = 0; fr < 2; ++fr) {
        int rb = rowBase + (wm << 5) + (fr << 4) + rq;
#pragma unroll
        for (int rg = 0; rg < 4; ++rg) {
            int r = rb + rg;
#pragma unroll
            for (int fc = 0; fc < 4; ++fc) {
                int cg = colBase + (fc << 4) + l15;
                outp[((size_t)r << 7) + cg] = acc[fr][fc][rg] + bias[cg];
            }
        }
    }
}

// ---------------- Final dot ----------------

__global__ __launch_bounds__(256) void k_dot(
    const float* __restrict__ P, const float* __restrict__ Q,
    float* __restrict__ out, int B) {
    int lane = threadIdx.x & 63;
    int b = (blockIdx.x << 2) + (threadIdx.x >> 6);
    if (b >= B) return;
    float2 p = *(const float2*)&P[(size_t)b * 128 + lane * 2];
    float2 q = *(const float2*)&Q[(size_t)b * 128 + lane * 2];
    float s = p.x * q.x + p.y * q.y;
#pragma unroll
    for (int off = 32; off; off >>= 1) s += __shfl_down(s, off);
    if (lane == 0) out[b] = s;
}

// ---------------- launch ----------------

extern "C" void kernel_launch(void* const* d_in, const int* in_sizes, int n_in,
                              void* d_out, int out_size, void* d_ws, size_t ws_size,
                              hipStream_t stream) {
    const float* x    = (const float*)d_in[0];
    const int*   edge = (const int*)d_in[1];
    const int*   sidx = (const int*)d_in[2];
    const int*   tidx = (const int*)d_in[3];
    const float* Wc0  = (const float*)d_in[4];
    const float* bc0  = (const float*)d_in[5];
    const float* Wc1  = (const float*)d_in[6];
    const float* bc1  = (const float*)d_in[7];
    const float* Wc2  = (const float*)d_in[8];
    const float* bc2  = (const float*)d_in[9];
    const float* Ww   = (const float*)d_in[10];
    const float* bw   = (const float*)d_in[11];
    const float* Wp   = (const float*)d_in[12];
    const float* bp   = (const float*)d_in[13];
    float* out = (float*)d_out;

    char* base = (char*)d_ws;
    size_t off = 0;
    auto alloc = [&](size_t bytes) -> char* {
        char* p = base + off;
        off = (off + bytes + 255) & ~(size_t)255;
        return p;
    };
    const size_t HSZ = (size_t)N_NODES * HID * sizeof(short);     // 25.6 MB
    const size_t XSZ = (size_t)2 * BATCH * HID * sizeof(short);   // 8.4 MB
    short* a1h  = (short*)alloc(HSZ);
    short* a1l  = (short*)alloc(HSZ);
    short* a2h  = (short*)alloc(HSZ);
    short* a2l  = (short*)alloc(HSZ);
    short* x3h  = (short*)alloc(XSZ);
    short* x3l  = (short*)alloc(XSZ);
    short* hbf  = (short*)alloc(HSZ);
    float* Pm   = (float*)alloc((size_t)BATCH * HID * sizeof(float));
    float* Qm   = (float*)alloc((size_t)BATCH * HID * sizeof(float));
    int*   offsets = (int*)alloc((size_t)(N_NODES + 1) * sizeof(int));
    int*   colArr  = (int*)alloc((size_t)N_EDGES * sizeof(int));
    unsigned* tmp  = (unsigned*)alloc((size_t)N_EDGES * sizeof(unsigned));
    float* dinv    = (float*)alloc((size_t)N_NODES * sizeof(float));
    int*   bcnt    = (int*)alloc(256 * sizeof(int));
    int*   bbase   = (int*)alloc(256 * sizeof(int));
    int*   bcur    = (int*)alloc(256 * sizeof(int));
    short* wtH     = (short*)alloc((size_t)9 * 16384 * sizeof(short));
    short* wtL     = (short*)alloc((size_t)9 * 16384 * sizeof(short));
    (void)ws_size; (void)in_sizes; (void)n_in; (void)out_size;

    // ---- CSR build ----
    hipMemsetAsync(bcnt, 0, NB * sizeof(int), stream);
    k_bhist<<<(N_EDGES + 4095) / 4096, 256, 0, stream>>>(edge + N_EDGES, bcnt, N_EDGES);
    k_bscan<<<1, 256, 0, stream>>>(bcnt, bbase, bcur, offsets);
    k_passA<<<(N_EDGES + EPB - 1) / EPB, 256, 0, stream>>>(edge, bcur, tmp, N_EDGES);
    k_passB<<<NB, 256, 0, stream>>>(tmp, bbase, offsets, dinv, colArr);

    // ---- weight prep ----
    k_prepW<<<9, 256, 0, stream>>>(Wc0, Wc1, Wc2, Wp, Ww, wtH, wtL);

    const int gridN  = (N_NODES + 63) / 64;    // 1563
    const int aggGrid  = (N_NODES + 3) / 4;    // 25000
    const int agg3Grid = (2 * BATCH) / 4;      // 8192
    const int dotGrid  = (BATCH + 3) / 4;      // 4096
#define WT(c) (wtH + (c) * 16384), (wtL + (c) * 16384)

    // ---- layer 1 ----
    k_rgemm32<<<gridN, 256, 0, stream>>>(x, WT(0), hbf, dinv, N_NODES);
    k_agg<<<aggGrid, 256, 0, stream>>>(hbf, colArr, offsets, dinv, bc0, a1h, a1l, N_NODES);

    // ---- layer 2 ----
    k_rgemm<<<gridN, 256, 0, stream>>>(a1h, a1l, WT(1), hbf, dinv, N_NODES);
    k_agg<<<aggGrid, 256, 0, stream>>>(hbf, colArr, offsets, dinv, bc1, a2h, a2l, N_NODES);

    // ---- layer 3 (batch nodes only) ----
    k_rgemm<<<gridN, 256, 0, stream>>>(a2h, a2l, WT(2), hbf, dinv, N_NODES);
    k_agg3<<<agg3Grid, 256, 0, stream>>>(hbf, colArr, offsets, dinv, bc2, x3h, x3l, sidx, tidx);

    // ---- fused P/Q + score ----
    k_pq<<<512, 256, 0, stream>>>(a1h, a1l, a2h, a2l, x3h, x3l, wtH, wtL,
                                  sidx, tidx, bp, bw, Pm, Qm);
    k_dot<<<dotGrid, 256, 0, stream>>>(Pm, Qm, out, BATCH);
}